// Round 8
// baseline (826.165 us; speedup 1.0000x reference)
//
#include <hip/hip_runtime.h>
#include <stdint.h>

typedef unsigned short u16;
typedef __bf16 bf16x8 __attribute__((ext_vector_type(8)));
typedef float  f32x4  __attribute__((ext_vector_type(4)));

#define B_ 4
#define L_ 4096
#define D_ 1024
#define H_ 16
#define TD 3072         // 3*D
#define NCHUNK 16
#define TCHUNK 256      // L_/NCHUNK
#define LDSPITCH 40     // 32 + 8 pad

__device__ __forceinline__ float bf2f(u16 h) {
    union { uint32_t u; float f; } v; v.u = ((uint32_t)h) << 16; return v.f;
}
__device__ __forceinline__ u16 f2bf(float f) {
    union { float f; uint32_t u; } v; v.f = f;
    uint32_t u = v.u;
    u += 0x7fffu + ((u >> 16) & 1u);   // round-to-nearest-even
    return (u16)(u >> 16);
}
__device__ __forceinline__ void unp8(uint4 u, float* f) {
    f[0] = bf2f((u16)(u.x)); f[1] = bf2f((u16)(u.x >> 16));
    f[2] = bf2f((u16)(u.y)); f[3] = bf2f((u16)(u.y >> 16));
    f[4] = bf2f((u16)(u.z)); f[5] = bf2f((u16)(u.z >> 16));
    f[6] = bf2f((u16)(u.w)); f[7] = bf2f((u16)(u.w >> 16));
}

// load 8 contiguous elements as 8 packed bf16 (uint4)
__device__ __forceinline__ uint4 ld8(const u16* p) { return *(const uint4*)p; }
__device__ __forceinline__ uint4 ld8(const float* p) {
    const float4 a = *(const float4*)p;
    const float4 b = *(const float4*)(p + 4);
    uint4 r;
    r.x = (uint32_t)f2bf(a.x) | ((uint32_t)f2bf(a.y) << 16);
    r.y = (uint32_t)f2bf(a.z) | ((uint32_t)f2bf(a.w) << 16);
    r.z = (uint32_t)f2bf(b.x) | ((uint32_t)f2bf(b.y) << 16);
    r.w = (uint32_t)f2bf(b.z) | ((uint32_t)f2bf(b.w) << 16);
    return r;
}

// store helper: C is bf16 (ws intermediate) or fp32 (final output)
__device__ __forceinline__ void stc(u16* p, float v)   { *p = f2bf(v); }
__device__ __forceinline__ void stc(float* p, float v) { *p = v; }

// ---------------------------------------------------------------------------
// NT GEMM: C(M,N) = bf16(A(M,K)) @ bf16(W(N,K))^T + bias(fp32).
// TA/TB: float (convert during staging) or u16 (already bf16). TC: u16|float.
// 128x128 tile, BK=32, 256 thr (4 waves), 4x4 16x16x32 MFMA per wave.
// Verified: r3(MFMA) == r4(fp32 oracle) bit-comparable on-device.
// ---------------------------------------------------------------------------
template <typename TA, typename TB, typename TC>
__global__ __launch_bounds__(256) void gemm_bt_bias(
    const TA* __restrict__ A, const TB* __restrict__ W,
    const float* __restrict__ bias, TC* __restrict__ C,
    int M, int N, int K)
{
    __shared__ u16 As[128 * LDSPITCH];
    __shared__ u16 Bs[128 * LDSPITCH];

    const int tid  = threadIdx.x;
    const int lane = tid & 63;
    const int wid  = tid >> 6;
    const int bm = blockIdx.y * 128;
    const int bn = blockIdx.x * 128;

    const int wm = (wid & 1) * 64;
    const int wn = (wid >> 1) * 64;
    const int fr   = lane & 15;
    const int quad = lane >> 4;

    // staging: thread t -> rows (t>>2) and (t>>2)+64, 8-elem k-group (t&3)
    const int srow = tid >> 2;          // 0..63
    const int sq   = tid & 3;           // 0..3
    const TA* Ag0 = A + (size_t)(bm + srow) * K + sq * 8;
    const TA* Ag1 = A + (size_t)(bm + 64 + srow) * K + sq * 8;
    const TB* Wg0 = W + (size_t)(bn + srow) * K + sq * 8;
    const TB* Wg1 = W + (size_t)(bn + 64 + srow) * K + sq * 8;

    f32x4 acc[4][4] = {};

    for (int k0 = 0; k0 < K; k0 += 32) {
        uint4 a0 = ld8(Ag0 + k0);
        uint4 a1 = ld8(Ag1 + k0);
        uint4 b0 = ld8(Wg0 + k0);
        uint4 b1 = ld8(Wg1 + k0);
        __syncthreads();
        *(uint4*)&As[srow * LDSPITCH + sq * 8]        = a0;
        *(uint4*)&As[(64 + srow) * LDSPITCH + sq * 8] = a1;
        *(uint4*)&Bs[srow * LDSPITCH + sq * 8]        = b0;
        *(uint4*)&Bs[(64 + srow) * LDSPITCH + sq * 8] = b1;
        __syncthreads();

        bf16x8 af[4], bfv[4];
#pragma unroll
        for (int tm = 0; tm < 4; ++tm) {
            int m = wm + tm * 16 + fr;
            af[tm] = *(const bf16x8*)&As[m * LDSPITCH + quad * 8];
        }
#pragma unroll
        for (int tn = 0; tn < 4; ++tn) {
            int n = wn + tn * 16 + fr;
            bfv[tn] = *(const bf16x8*)&Bs[n * LDSPITCH + quad * 8];
        }
#pragma unroll
        for (int tm = 0; tm < 4; ++tm)
#pragma unroll
            for (int tn = 0; tn < 4; ++tn)
                acc[tm][tn] = __builtin_amdgcn_mfma_f32_16x16x32_bf16(
                    af[tm], bfv[tn], acc[tm][tn], 0, 0, 0);
    }

    // epilogue: C/D layout col=lane&15, row=quad*4+reg (m89/m91-verified)
#pragma unroll
    for (int tm = 0; tm < 4; ++tm) {
#pragma unroll
        for (int tn = 0; tn < 4; ++tn) {
            const int col = bn + wn + tn * 16 + fr;
            const float bv = bias[col];
#pragma unroll
            for (int r = 0; r < 4; ++r) {
                const int row = bm + wm + tm * 16 + quad * 4 + r;
                stc(&C[(size_t)row * N + col], acc[tm][tn][r] + bv);
            }
        }
    }
}

// ---------------------------------------------------------------------------
// STP scan, chunked linear recurrence (on-device verified == naive scan).
// state[i][j] <- R*state + (Gam/8)*v_i*k_j; y_i = sum_j (W+S)_ij q_j.
// Thread (i=t/4, jc=t&3) owns state row i, cols jc*16..+16 in fp32 regs.
// ---------------------------------------------------------------------------
__global__ __launch_bounds__(256) void stp_scan_local(
    const u16* __restrict__ qkv, const float* __restrict__ Lam,
    const float* __restrict__ Gam, float* __restrict__ F)
{
    const int c = blockIdx.x, h = blockIdx.y, b = blockIdx.z;
    const int t = threadIdx.x;
    const int i = t >> 2, jc = t & 3, j0 = jc << 4;
    const int hij = (h << 12) + (i << 6) + j0;

    float R[16], Gv[16], s[16];
#pragma unroll
    for (int j = 0; j < 16; ++j) {
        R[j]  = 1.0f / (1.0f + expf(Lam[hij + j]));  // 1-sigmoid(x)=sigmoid(-x)
        Gv[j] = Gam[hij + j] * 0.125f;               // fold k scale 1/sqrt(64)
        s[j]  = 0.0f;
    }

    const u16* rowp = qkv + (size_t)(b * L_ + c * TCHUNK) * TD;
    const int koff = D_ + (h << 6) + j0;
    const int voff = 2 * D_ + (h << 6) + i;

    for (int tt = 0; tt < TCHUNK; ++tt, rowp += TD) {
        const float v = bf2f(rowp[voff]);
        uint4 ku0 = *(const uint4*)(rowp + koff);
        uint4 ku1 = *(const uint4*)(rowp + koff + 8);
        float kf[16];
        unp8(ku0, kf); unp8(ku1, kf + 8);
#pragma unroll
        for (int j = 0; j < 16; ++j)
            s[j] = fmaf(R[j], s[j], (Gv[j] * v) * kf[j]);
    }

    float* Fp = F + (((size_t)(b * H_ + h) * NCHUNK + c) << 12) + (i << 6) + j0;
#pragma unroll
    for (int j = 0; j < 16; j += 4)
        *(f32x4*)(Fp + j) = *(const f32x4*)(s + j);
}

// Sequential chunk combine per (b,h), in place: F[c] becomes Sinit[c]
// (state BEFORE chunk c). Sinit[c] = Rt ⊙ Sinit[c-1] + F[c-1], Rt = R^TCHUNK.
__global__ __launch_bounds__(256) void stp_combine(
    const float* __restrict__ Lam, float* __restrict__ F)
{
    const int h = blockIdx.x, b = blockIdx.y;
    const int t = threadIdx.x;
    const int i = t >> 2, jc = t & 3, j0 = jc << 4;
    const int hij = (h << 12) + (i << 6) + j0;

    float Rt[16], s[16];
#pragma unroll
    for (int j = 0; j < 16; ++j) {
        float R = 1.0f / (1.0f + expf(Lam[hij + j]));
        Rt[j] = powf(R, (float)TCHUNK);
        s[j] = 0.0f;
    }
    float* base = F + (((size_t)(b * H_ + h) * NCHUNK) << 12) + (i << 6) + j0;
    for (int c = 0; c < NCHUNK; ++c) {
        float* p = base + ((size_t)c << 12);
        float tmp[16];
#pragma unroll
        for (int j = 0; j < 16; ++j) tmp[j] = p[j];
#pragma unroll
        for (int j = 0; j < 16; ++j) { p[j] = s[j]; s[j] = fmaf(Rt[j], s[j], tmp[j]); }
    }
}

__global__ __launch_bounds__(256) void stp_scan_out(
    const u16* __restrict__ qkv, const float* __restrict__ Lam,
    const float* __restrict__ Gam, const float* __restrict__ Wst,
    const float* __restrict__ Sinit, u16* __restrict__ y)
{
    const int c = blockIdx.x, h = blockIdx.y, b = blockIdx.z;
    const int t = threadIdx.x;
    const int i = t >> 2, jc = t & 3, j0 = jc << 4;
    const int hij = (h << 12) + (i << 6) + j0;

    float R[16], Gv[16], Wr[16], s[16];
    const float* Sp = Sinit + (((size_t)(b * H_ + h) * NCHUNK + c) << 12) + (i << 6) + j0;
#pragma unroll
    for (int j = 0; j < 16; ++j) {
        R[j]  = 1.0f / (1.0f + expf(Lam[hij + j]));
        Gv[j] = Gam[hij + j] * 0.125f;
        Wr[j] = Wst[hij + j];
        s[j]  = Sp[j];
    }

    const u16* rowp = qkv + (size_t)(b * L_ + c * TCHUNK) * TD;
    const int qoff = (h << 6) + j0;
    const int koff = D_ + qoff;
    const int voff = 2 * D_ + (h << 6) + i;
    u16* yp = y + (size_t)(b * L_ + c * TCHUNK) * D_ + (h << 6) + i;

    for (int tt = 0; tt < TCHUNK; ++tt, rowp += TD, yp += D_) {
        const float v = bf2f(rowp[voff]);
        uint4 qu0 = *(const uint4*)(rowp + qoff);
        uint4 qu1 = *(const uint4*)(rowp + qoff + 8);
        uint4 ku0 = *(const uint4*)(rowp + koff);
        uint4 ku1 = *(const uint4*)(rowp + koff + 8);
        float kf[16], qf[16];
        unp8(ku0, kf); unp8(ku1, kf + 8);
        unp8(qu0, qf); unp8(qu1, qf + 8);

        float ya = 0.0f, yb = 0.0f;
#pragma unroll
        for (int j = 0; j < 16; j += 2) {
            s[j]     = fmaf(R[j],     s[j],     (Gv[j]     * v) * kf[j]);
            s[j + 1] = fmaf(R[j + 1], s[j + 1], (Gv[j + 1] * v) * kf[j + 1]);
            ya = fmaf(Wr[j]     + s[j],     qf[j],     ya);
            yb = fmaf(Wr[j + 1] + s[j + 1], qf[j + 1], yb);
        }
        float yacc = ya + yb;
        yacc += __shfl_xor(yacc, 1, 64);
        yacc += __shfl_xor(yacc, 2, 64);
        if (jc == 0) *yp = f2bf(yacc);
    }
}

__global__ void zero_out_f32(float* p, size_t n) {
    size_t i = (size_t)blockIdx.x * blockDim.x + threadIdx.x;
    if (i < n) p[i] = 0.0f;
}

// ---------------------------------------------------------------------------
extern "C" void kernel_launch(void* const* d_in, const int* in_sizes, int n_in,
                              void* d_out, int out_size, void* d_ws, size_t ws_size,
                              hipStream_t stream)
{
    const float* x      = (const float*)d_in[0];
    const float* Wqkv_w = (const float*)d_in[1];
    const float* Wqkv_b = (const float*)d_in[2];
    const float* out_w  = (const float*)d_in[3];
    const float* out_b  = (const float*)d_in[4];
    const float* Wst    = (const float*)d_in[5];
    const float* Lam    = (const float*)d_in[6];
    const float* Gam    = (const float*)d_in[7];
    float* out = (float*)d_out;                    // fp32 output (r7 probe-proven)

    // ws carve (151.0 MB): qkv bf16 | y bf16 | F fp32 (reused as Sinit)
    const size_t need = (size_t)B_ * L_ * TD * 2 + (size_t)B_ * L_ * D_ * 2
                      + (size_t)B_ * H_ * NCHUNK * 64 * 64 * 4;
    if (ws_size < need) {
        zero_out_f32<<<(out_size + 255) / 256, 256, 0, stream>>>(out, (size_t)out_size);
        return;
    }
    u16*   qkv = (u16*)d_ws;                                  // 50331648 elems
    u16*   y   = qkv + (size_t)B_ * L_ * TD;                  // 16777216 elems
    float* F   = (float*)(y + (size_t)B_ * L_ * D_);          //  4194304 floats

    gemm_bt_bias<float, float, u16><<<dim3(TD / 128, (B_ * L_) / 128), 256, 0, stream>>>(
        x, Wqkv_w, Wqkv_b, qkv, B_ * L_, TD, D_);
    stp_scan_local<<<dim3(NCHUNK, H_, B_), 256, 0, stream>>>(qkv, Lam, Gam, F);
    stp_combine<<<dim3(H_, B_), 256, 0, stream>>>(Lam, F);
    stp_scan_out<<<dim3(NCHUNK, H_, B_), 256, 0, stream>>>(qkv, Lam, Gam, Wst, F, y);
    gemm_bt_bias<u16, float, float><<<dim3(D_ / 128, (B_ * L_) / 128), 256, 0, stream>>>(
        y, out_w, out_b, out, B_ * L_, D_, D_);
}